// Round 2
// 571.240 us; speedup vs baseline: 1.0129x; 1.0129x over previous
//
#include <hip/hip_runtime.h>

#define EPS 1e-3f

typedef _Float16 f16;
typedef _Float16 f16x8 __attribute__((ext_vector_type(8)));
typedef _Float16 f16x4 __attribute__((ext_vector_type(4)));
typedef float f32x4 __attribute__((ext_vector_type(4)));

// problem sizes
constexpr int Bn = 8, C = 512, C8 = 64;
constexpr int N = 16384;          // Z*H*W
constexpr int M = Bn * N;         // 131072 rows

// ws layout (bytes), 16B-aligned
constexpr size_t OFF_WHI  = 0;                              // f16 [192][512] folded qkv weights (hi)
constexpr size_t OFF_WLO  = 196608;                         // f16 [128][512] folded q,k weights (lo*2048)
constexpr size_t OFF_BQKV = 327680;                         // f32 [192]
constexpr size_t OFF_WPT  = 328704;                         // f16 [512][64]  folded proj weight^T
constexpr size_t OFF_BOUT = 394240;                         // f32 [512]
constexpr size_t OFF_V    = 396288;                         // f16 [131072][64]
constexpr size_t OFF_S    = OFF_V + (size_t)M * 64 * 2;     // f32 [8 part][8 b][4096] gram partials
constexpr size_t OFF_BT   = OFF_S + (size_t)8 * 8 * 4096 * 4; // f16 [8][64][64] beta^T: bt[i][m]=beta[m][i]

// ---------------- K0: fold BN into weights + zero gram partial buffer ----------------
__global__ __launch_bounds__(256) void k0_fold(
    const float* g1, const float* be1, const float* mu1, const float* va1,
    const float* wq, const float* bq, const float* wk, const float* bk,
    const float* wv, const float* bv, const float* wp, const float* bp,
    const float* g2, const float* be2, const float* mu2, const float* va2,
    char* ws)
{
  f16* whi = (f16*)(ws + OFF_WHI);
  f16* wlo = (f16*)(ws + OFF_WLO);
  float* bqkv = (float*)(ws + OFF_BQKV);
  f16* wpt = (f16*)(ws + OFF_WPT);
  float* bout = (float*)(ws + OFF_BOUT);
  float* sbuf = (float*)(ws + OFF_S);
  __shared__ float red[256];
  int blk = blockIdx.x, t = threadIdx.x;
  if (blk < 192) {
    const float* w; const float* bb; int col;
    if (blk < 64)       { w = wq; bb = bq; col = blk; }
    else if (blk < 128) { w = wk; bb = bk; col = blk - 64; }
    else                { w = wv; bb = bv; col = blk - 128; }
    float part = 0.f;
    for (int c = t; c < 512; c += 256) {
      float a1 = g1[c] * rsqrtf(va1[c] + EPS);
      float d1 = be1[c] - mu1[c] * a1;
      float wval = w[c * 64 + col];
      float fw = a1 * wval;
      f16 hi = (f16)fw;
      whi[blk * 512 + c] = hi;
      if (blk < 128) wlo[blk * 512 + c] = (f16)((fw - (float)hi) * 2048.0f);
      part += d1 * wval;
    }
    red[t] = part; __syncthreads();
    for (int s = 128; s > 0; s >>= 1) { if (t < s) red[t] += red[t + s]; __syncthreads(); }
    if (t == 0) bqkv[blk] = red[0] + bb[col];
  } else {
    int co = blk - 192;  // 0..511
    float a2 = g2[co] * rsqrtf(va2[co] + EPS);
    if (t < 64) wpt[co * 64 + t] = (f16)(wp[t * 512 + co] * a2);
    if (t == 0) bout[co] = (bp[co] - mu2[co]) * a2 + be2[co];
    // zero the 8x8x4096 gram partial buffer (512 blocks x 512 floats)
    sbuf[co * 512 + t] = 0.0f;
    sbuf[co * 512 + 256 + t] = 0.0f;
  }
}

// ---------------- K1: fused BN1 + QKV GEMM + gram partial ----------------
// Main GEMM loop unchanged (double-buffered LDS, one barrier per 64-k chunk).
// Epilogue: q,k never leave the block. They're transposed into the (dead)
// xs LDS buffers, an 8-MFMA/wave 64x64x64 gram tile is computed, and f32
// partials are atomically accumulated into 8 rotating partial buffers.
// This kills the 33.5 MB qkbuf write AND the entire K2a gather kernel.
__global__ __launch_bounds__(256, 2) void k1_qkv(const float* __restrict__ x, char* __restrict__ ws)
{
  const f16* whi = (const f16*)(ws + OFF_WHI);
  const f16* wlo = (const f16*)(ws + OFF_WLO);
  const float* bqkv = (const float*)(ws + OFF_BQKV);
  f16* vbuf  = (f16*)(ws + OFF_V);
  float* spart = (float*)(ws + OFF_S);

  __shared__ f16 xs[2][64 * 72];   // 64 rows x 64 cols, stride 72 (16B-aligned b128 reads)

  int t = threadIdx.x;
  int wave = t >> 6, lane = t & 63;
  int m0 = blockIdx.x * 64;

  // staging: thread -> row t>>2, cols (t&3)*4 + {0,16,32,48}; lanes 0..3 = 64B contiguous
  int srow = t >> 2, scol = (t & 3) * 4;
  const float* xg = x + (size_t)(m0 + srow) * 512 + scol;

  int bn0 = wave * 16 + (lane & 15);   // q col tile
  int bn1 = bn0 + 64;                  // k col tile
  int bn2 = bn0 + 128;                 // v col tile
  int klane = (lane >> 4) * 8;

  f32x4 acc_h[4][2], acc_l[4][2], acc_v[4];
  for (int i = 0; i < 4; i++) {
    for (int j = 0; j < 2; j++) { acc_h[i][j] = (f32x4){0.f,0.f,0.f,0.f}; acc_l[i][j] = (f32x4){0.f,0.f,0.f,0.f}; }
    acc_v[i] = (f32x4){0.f,0.f,0.f,0.f};
  }

  f32x4 a0 = *(const f32x4*)(xg);
  f32x4 a1 = *(const f32x4*)(xg + 16);
  f32x4 a2 = *(const f32x4*)(xg + 32);
  f32x4 a3 = *(const f32x4*)(xg + 48);

  for (int iter = 0; iter < 8; iter++) {
    f16* xb = &xs[iter & 1][0];
    {
      f16x4 h0, h1, h2, h3;
      for (int e = 0; e < 4; e++) { h0[e]=(f16)a0[e]; h1[e]=(f16)a1[e]; h2[e]=(f16)a2[e]; h3[e]=(f16)a3[e]; }
      *(f16x4*)&xb[srow * 72 + scol     ] = h0;
      *(f16x4*)&xb[srow * 72 + scol + 16] = h1;
      *(f16x4*)&xb[srow * 72 + scol + 32] = h2;
      *(f16x4*)&xb[srow * 72 + scol + 48] = h3;
    }
    __syncthreads();
    if (iter < 7) {
      const float* xi = xg + (iter + 1) * 64;
      a0 = *(const f32x4*)(xi);
      a1 = *(const f32x4*)(xi + 16);
      a2 = *(const f32x4*)(xi + 32);
      a3 = *(const f32x4*)(xi + 48);
    }
    for (int ks = 0; ks < 2; ks++) {
      int kg = iter * 64 + ks * 32 + klane;
      f16x8 b0h = *(const f16x8*)(whi + bn0 * 512 + kg);
      f16x8 b1h = *(const f16x8*)(whi + bn1 * 512 + kg);
      f16x8 b2h = *(const f16x8*)(whi + bn2 * 512 + kg);
      f16x8 b0l = *(const f16x8*)(wlo + bn0 * 512 + kg);
      f16x8 b1l = *(const f16x8*)(wlo + bn1 * 512 + kg);
      int aoff = (lane & 15) * 72 + ks * 32 + klane;
      for (int mt = 0; mt < 4; mt++) {
        f16x8 af = *(const f16x8*)&xb[mt * 16 * 72 + aoff];
        acc_h[mt][0] = __builtin_amdgcn_mfma_f32_16x16x32_f16(af, b0h, acc_h[mt][0], 0, 0, 0);
        acc_h[mt][1] = __builtin_amdgcn_mfma_f32_16x16x32_f16(af, b1h, acc_h[mt][1], 0, 0, 0);
        acc_l[mt][0] = __builtin_amdgcn_mfma_f32_16x16x32_f16(af, b0l, acc_l[mt][0], 0, 0, 0);
        acc_l[mt][1] = __builtin_amdgcn_mfma_f32_16x16x32_f16(af, b1l, acc_l[mt][1], 0, 0, 0);
        acc_v[mt]    = __builtin_amdgcn_mfma_f32_16x16x32_f16(af, b2h, acc_v[mt],    0, 0, 0);
      }
    }
  }

  // ---- epilogue: v -> global; q,k -> LDS transposed; gram tile; atomic partials ----
  const float inv2048 = 1.0f / 2048.0f;
  float bA = bqkv[bn0], bB = bqkv[bn1], bV = bqkv[bn2];
  f16* qT = &xs[0][0];   // [64 col][72] stride-padded: qT[i][n] = q[m0+n, i]
  f16* kT = &xs[1][0];   // [64 col][72]: kT[j][n] = k[m0+n, j]
  __syncthreads();       // all waves done reading xs from the last iteration
  for (int mt = 0; mt < 4; mt++)
    for (int r = 0; r < 4; r++) {
      int n = (lane >> 4) * 4 + mt * 16 + r;            // local row 0..63
      size_t row = (size_t)(m0 + n);
      float qv = acc_h[mt][0][r] + acc_l[mt][0][r] * inv2048 + bA;
      float kv = acc_h[mt][1][r] + acc_l[mt][1][r] * inv2048 + bB;
      qT[bn0 * 72 + n] = (f16)qv;
      kT[bn0 * 72 + n] = (f16)kv;
      vbuf[row * 64 + bn0] = (f16)(acc_v[mt][r] + bV);
    }
  __syncthreads();

  // gram: s[i,j] += sum_{n in block} q[n,i] k[n,j]; wave owns j-tile = wave
  f32x4 gacc[4];
  for (int i = 0; i < 4; i++) gacc[i] = (f32x4){0.f,0.f,0.f,0.f};
  for (int ks = 0; ks < 2; ks++) {
    f16x8 bfr = *(const f16x8*)&kT[(wave * 16 + (lane & 15)) * 72 + ks * 32 + klane];
    for (int it = 0; it < 4; it++) {
      f16x8 afr = *(const f16x8*)&qT[(it * 16 + (lane & 15)) * 72 + ks * 32 + klane];
      gacc[it] = __builtin_amdgcn_mfma_f32_16x16x32_f16(afr, bfr, gacc[it], 0, 0, 0);
    }
  }
  int b = blockIdx.x >> 8;          // 256 blocks per batch
  int g = blockIdx.x & 7;           // rotating partial buffer
  float* sdst = spart + ((size_t)(g * 8 + b)) * 4096;
  int j = wave * 16 + (lane & 15);
  for (int it = 0; it < 4; it++)
    for (int r = 0; r < 4; r++) {
      int i = it * 16 + (lane >> 4) * 4 + r;
      atomicAdd(&sdst[i * 64 + j], gacc[it][r]);
    }
}

// ---------------- K2b: reduce partials -> softmax -> beta^T (fp16) ----------------
__global__ __launch_bounds__(256) void k2b_softmax(char* __restrict__ ws)
{
  const float* spart = (const float*)(ws + OFF_S);
  f16* bt = (f16*)(ws + OFF_BT);
  __shared__ float red[64][4];

  int b = blockIdx.x, t = threadIdx.x;
  int m = t & 63, qd = t >> 6;      // row, quarter (16 j each)

  // reduce the 8 partials for this (m, quarter)
  float sv[16];
  {
    const float* base = spart + (size_t)b * 4096 + (size_t)m * 64 + qd * 16;
    f32x4 v0 = (f32x4){0.f,0.f,0.f,0.f}, v1 = v0, v2 = v0, v3 = v0;
    for (int g = 0; g < 8; g++) {
      const f32x4* p = (const f32x4*)(base + (size_t)g * 8 * 4096);
      v0 += p[0]; v1 += p[1]; v2 += p[2]; v3 += p[3];
    }
    for (int e = 0; e < 4; e++) { sv[e] = v0[e]; sv[4+e] = v1[e]; sv[8+e] = v2[e]; sv[12+e] = v3[e]; }
  }
  float mx = sv[0];
  for (int jj = 1; jj < 16; jj++) mx = fmaxf(mx, sv[jj]);
  red[m][qd] = mx; __syncthreads();
  float rmx = fmaxf(fmaxf(red[m][0], red[m][1]), fmaxf(red[m][2], red[m][3]));
  __syncthreads();
  float s = 0.f;
  for (int jj = 0; jj < 16; jj++) { float e = __expf(sv[jj] - rmx); sv[jj] = e; s += e; }
  red[m][qd] = s; __syncthreads();
  float inv = 1.0f / (red[m][0] + red[m][1] + red[m][2] + red[m][3]);
  // beta[m][j] -> bt[j][m]; j = qd*16+jj. Threads with same qd span m=0..63 ->
  // 64 consecutive u16 per jj = coalesced 128B stores.
  for (int jj = 0; jj < 16; jj++)
    bt[(size_t)b * 4096 + (qd * 16 + jj) * 64 + m] = (f16)(sv[jj] * inv);
}

// ---------------- K34: fused attn + projection + BN2 ----------------
// grid 1024 = 8b x 128 j-chunks(128). Phase1: attn tile (64i x 128j) = beta^T.v^T
// -> the flat reshape makes this exactly 128 contiguous pos-rows x 64 d ->
// XOR-swizzled LDS (conflict-free b16 writes, aligned b128 reads). Phase2:
// projection GEMM 128x512x64 + bias, streamed to out.
__device__ __forceinline__ int at_idx(int row, int d) {
  int dd = (d >> 1) ^ (((row >> 3) & 3) << 3);
  return row * 64 + dd * 2 + (d & 1);
}

__global__ __launch_bounds__(256, 2) void k34_attn_proj(char* __restrict__ ws, float* __restrict__ out)
{
  const f16* vbuf = (const f16*)(ws + OFF_V);
  const f16* bt = (const f16*)(ws + OFF_BT);
  const f16* wpt = (const f16*)(ws + OFF_WPT);
  const float* bout = (const float*)(ws + OFF_BOUT);
  __shared__ f16 at[128 * 64];   // 16 KB, xor-swizzled

  int t = threadIdx.x, wave = t >> 6, lane = t & 63;
  int b = blockIdx.x >> 7, jc = blockIdx.x & 127;
  int li = lane & 15;
  int klane = (lane >> 4) * 8;

  // ---- phase 1: attn[i, j] for i=0..63, j = jc*128 .. +127 (wave owns 32 j) ----
  f32x4 acc[4][2];
  for (int i = 0; i < 4; i++) for (int j = 0; j < 2; j++) acc[i][j] = (f32x4){0.f,0.f,0.f,0.f};

  for (int km = 0; km < 2; km++) {
    f16x8 af[4], bf[2];
    for (int it = 0; it < 4; it++)
      af[it] = *(const f16x8*)(bt + (size_t)b * 4096 + (it * 16 + li) * 64 + km * 32 + klane);
    for (int jt = 0; jt < 2; jt++) {
      int jrow = jc * 128 + wave * 32 + jt * 16 + li;
      bf[jt] = *(const f16x8*)(vbuf + (size_t)(b * 16384 + jrow) * 64 + km * 32 + klane);
    }
    for (int it = 0; it < 4; it++)
      for (int jt = 0; jt < 2; jt++)
        acc[it][jt] = __builtin_amdgcn_mfma_f32_16x16x32_f16(af[it], bf[jt], acc[it][jt], 0, 0, 0);
  }
  // scatter to LDS: row_local = i*2 + (wave>>1), d = (wave&1)*32 + jt*16 + li
  for (int it = 0; it < 4; it++)
    for (int jt = 0; jt < 2; jt++)
      for (int r = 0; r < 4; r++) {
        int i = it * 16 + (lane >> 4) * 4 + r;
        int d = (wave & 1) * 32 + jt * 16 + li;
        at[at_idx(i * 2 + (wave >> 1), d)] = (f16)acc[it][jt][r];
      }
  __syncthreads();

  // ---- phase 2: out[pos, c] = sum_d attn[pos, d] * wpt[c][d] + bout[c] ----
  // wave owns rows wave*32 .. +31 (2 m-tiles); c in 8 strips of 64.
  f16x8 paf[2][2];
  for (int mt = 0; mt < 2; mt++)
    for (int km = 0; km < 2; km++) {
      int row = wave * 32 + mt * 16 + li;
      int d = km * 32 + klane;
      paf[mt][km] = *(const f16x8*)&at[row * 64 + ((((d >> 1) ^ (((row >> 3) & 3) << 3))) << 1)];
    }
  size_t obase = (size_t)b * 16384 * 512;
  for (int strip = 0; strip < 8; strip++) {
    int c0 = strip * 64;
    f16x8 pbf[2][4];
    for (int nt = 0; nt < 4; nt++)
      for (int km = 0; km < 2; km++)
        pbf[km][nt] = *(const f16x8*)(wpt + (size_t)(c0 + nt * 16 + li) * 64 + km * 32 + klane);
    f32x4 pac[2][4];
    for (int mt = 0; mt < 2; mt++) for (int nt = 0; nt < 4; nt++) pac[mt][nt] = (f32x4){0.f,0.f,0.f,0.f};
    for (int km = 0; km < 2; km++)
      for (int mt = 0; mt < 2; mt++)
        for (int nt = 0; nt < 4; nt++)
          pac[mt][nt] = __builtin_amdgcn_mfma_f32_16x16x32_f16(paf[mt][km], pbf[km][nt], pac[mt][nt], 0, 0, 0);
    for (int nt = 0; nt < 4; nt++) {
      int c = c0 + nt * 16 + li;
      float bc = bout[c];
      for (int mt = 0; mt < 2; mt++)
        for (int r = 0; r < 4; r++) {
          int rl = wave * 32 + mt * 16 + (lane >> 4) * 4 + r;
          int pos = (rl >> 1) * 256 + jc * 2 + (rl & 1);
          out[obase + (size_t)pos * 512 + c] = pac[mt][nt][r] + bc;
        }
    }
  }
}

extern "C" void kernel_launch(void* const* d_in, const int* in_sizes, int n_in,
                              void* d_out, int out_size, void* d_ws, size_t ws_size,
                              hipStream_t stream)
{
  const float* x   = (const float*)d_in[0];
  const float* g1  = (const float*)d_in[1];
  const float* be1 = (const float*)d_in[2];
  const float* mu1 = (const float*)d_in[3];
  const float* va1 = (const float*)d_in[4];
  const float* wq  = (const float*)d_in[5];
  const float* bq  = (const float*)d_in[6];
  const float* wk  = (const float*)d_in[7];
  const float* bk  = (const float*)d_in[8];
  const float* wv  = (const float*)d_in[9];
  const float* bv  = (const float*)d_in[10];
  const float* wp  = (const float*)d_in[11];
  const float* bp  = (const float*)d_in[12];
  const float* g2  = (const float*)d_in[13];
  const float* be2 = (const float*)d_in[14];
  const float* mu2 = (const float*)d_in[15];
  const float* va2 = (const float*)d_in[16];
  char* ws = (char*)d_ws;
  float* out = (float*)d_out;

  k0_fold<<<dim3(704), dim3(256), 0, stream>>>(g1, be1, mu1, va1, wq, bq, wk, bk,
                                               wv, bv, wp, bp, g2, be2, mu2, va2, ws);
  k1_qkv<<<dim3(2048), dim3(256), 0, stream>>>(x, ws);
  k2b_softmax<<<dim3(8), dim3(256), 0, stream>>>(ws);
  k34_attn_proj<<<dim3(1024), dim3(256), 0, stream>>>(ws, out);
}